// Round 1
// baseline (5875.826 us; speedup 1.0000x reference)
//
#include <hip/hip_runtime.h>
#include <math.h>

#define B_ 8
#define N_ 512
#define T_ 64
#define NIN_ 64
#define NE_ 128
#define NH_ 128
#define NR_ 4096   // B*N

__device__ __forceinline__ float sigm(float x) {
  x = fminf(fmaxf(x, -30.f), 30.f);
  return 1.f / (1.f + __expf(-x));
}
__device__ __forceinline__ float tanh_fast(float x) {
  x = fminf(fmaxf(x, -15.f), 15.f);
  float e = __expf(2.f * x);
  return (e - 1.f) / (e + 1.f);
}

// ---------------- setup kernels ----------------

// dinv[row] = d>0 ? rsqrt(rowsum(A)) : 0 ; one wave per row
__global__ __launch_bounds__(256) void k_dinv(const float* __restrict__ A,
                                              float* __restrict__ dinv) {
  int row = blockIdx.x * 4 + (threadIdx.x >> 6);
  int lane = threadIdx.x & 63;
  const float* a = A + (size_t)row * N_;
  float s = 0.f;
  for (int j = lane; j < N_; j += 64) s += a[j];
  #pragma unroll
  for (int off = 32; off > 0; off >>= 1) s += __shfl_down(s, off);
  if (lane == 0) dinv[row] = (s > 0.f) ? rsqrtf(s) : 0.f;
}

// WU (256 x 512): rows 0:128 = W*[128:256] (eh part), rows 128:256 = Wh*
__global__ __launch_bounds__(256) void k_wu(
    const float* __restrict__ Wii, const float* __restrict__ Wif,
    const float* __restrict__ Wig, const float* __restrict__ Wio,
    const float* __restrict__ Whi, const float* __restrict__ Whf,
    const float* __restrict__ Whg, const float* __restrict__ Who,
    float* __restrict__ WU) {
  int idx = blockIdx.x * 256 + threadIdx.x;   // < 131072
  int k = idx >> 9, col = idx & 511, g = col >> 7, j = col & 127;
  const float* Wx = (g == 0) ? Wii : (g == 1) ? Wif : (g == 2) ? Wig : Wio;
  const float* Wh = (g == 0) ? Whi : (g == 1) ? Whf : (g == 2) ? Whg : Who;
  WU[idx] = (k < 128) ? Wx[(size_t)(128 + k) * NH_ + j]
                      : Wh[(size_t)(k - 128) * NH_ + j];
}

// bcat[col] = bx + bh + bpe @ W*[128:256]   (col = g*128+j)
__global__ __launch_bounds__(256) void k_bcat(
    const float* __restrict__ bii, const float* __restrict__ bif,
    const float* __restrict__ big, const float* __restrict__ bio,
    const float* __restrict__ bhi, const float* __restrict__ bhf,
    const float* __restrict__ bhg, const float* __restrict__ bho,
    const float* __restrict__ bpe,
    const float* __restrict__ Wii, const float* __restrict__ Wif,
    const float* __restrict__ Wig, const float* __restrict__ Wio,
    float* __restrict__ bcat) {
  int col = blockIdx.x * 256 + threadIdx.x;   // < 512
  int g = col >> 7, j = col & 127;
  const float* bx = (g == 0) ? bii : (g == 1) ? bif : (g == 2) ? big : bio;
  const float* bh = (g == 0) ? bhi : (g == 1) ? bhf : (g == 2) ? bhg : bho;
  const float* Wx = (g == 0) ? Wii : (g == 1) ? Wif : (g == 2) ? Wig : Wio;
  float s = bx[j] + bh[j];
  for (int k = 0; k < NE_; k++) s += bpe[k] * Wx[(size_t)(128 + k) * NH_ + j];
  bcat[col] = s;
}

// es = X0@Wse + bse ; espre = es@W*[0:128] + bcat ; out[:, t=0] = X0
__global__ __launch_bounds__(256) void k_espre(
    const float* __restrict__ X, const float* __restrict__ Wse,
    const float* __restrict__ bse,
    const float* __restrict__ Wii, const float* __restrict__ Wif,
    const float* __restrict__ Wig, const float* __restrict__ Wio,
    const float* __restrict__ bcat,
    float* __restrict__ espre, float* __restrict__ out) {
  __shared__ float x0[16][64];
  __shared__ float es[16][128];
  const int t = threadIdx.x;
  const int row0 = blockIdx.x * 16;
  for (int i = t; i < 1024; i += 256) {
    int r = i >> 6, c = i & 63;
    float v = X[((size_t)(row0 + r) * T_) * NIN_ + c];
    x0[r][c] = v;
    out[((size_t)(row0 + r) * T_) * NIN_ + c] = v;
  }
  __syncthreads();
  for (int i = t; i < 2048; i += 256) {
    int r = i >> 7, j = i & 127;
    float s = bse[j];
    for (int k = 0; k < NIN_; k++) s += x0[r][k] * Wse[(size_t)k * NE_ + j];
    es[r][j] = s;
  }
  __syncthreads();
  for (int i = t; i < 8192; i += 256) {
    int r = i >> 9, col = i & 511, g = col >> 7, j = col & 127;
    const float* Wx = (g == 0) ? Wii : (g == 1) ? Wif : (g == 2) ? Wig : Wio;
    float s = bcat[col];
    for (int k = 0; k < NE_; k++) s += es[r][k] * Wx[(size_t)k * NH_ + j];
    espre[(size_t)(row0 + r) * 512 + col] = s;
  }
}

// ---------------- per-step kernels ----------------

// Hp_half = dinv_i * A[:, krange] @ (dinv_j * hp[krange, :])
// grid: b(8) x rowtile(16, 32 rows each) x ksplit(2) = 256 blocks
__global__ __launch_bounds__(256) void k_graph(
    const float* __restrict__ A, const float* __restrict__ dinv,
    const float* __restrict__ hp,
    float* __restrict__ Hpa, float* __restrict__ Hpb) {
  __shared__ float As[32][68];
  __shared__ float hps[64][128];
  const int t = threadIdx.x;
  const int b = blockIdx.x >> 5;
  const int rt = (blockIdx.x >> 1) & 15;
  const int ks = blockIdx.x & 1;
  const int row0 = rt * 32;                 // within batch
  const int tc = t & 31, tr = t >> 5;       // cols tc*4, rows tr*4+{0..3}
  float4 acc[4];
  #pragma unroll
  for (int r = 0; r < 4; r++) acc[r] = make_float4(0.f, 0.f, 0.f, 0.f);
  const size_t abase = ((size_t)b * N_ + row0) * N_;
  for (int kt = 0; kt < 4; kt++) {
    const int k0 = ks * 256 + kt * 64;
    __syncthreads();
    #pragma unroll
    for (int i = 0; i < 2; i++) {           // A tile 32x64
      int idx = t + i * 256;
      int r = idx >> 4, c4 = idx & 15;
      *(float4*)&As[r][c4 * 4] =
          *(const float4*)&A[abase + (size_t)r * N_ + k0 + c4 * 4];
    }
    #pragma unroll
    for (int i = 0; i < 8; i++) {           // hp tile 64x128, scaled by dinv_j
      int idx = t + i * 256;
      int jr = idx >> 5, c4 = idx & 31;
      int j = b * N_ + k0 + jr;
      float s = dinv[j];
      float4 v = *(const float4*)&hp[(size_t)j * 128 + c4 * 4];
      v.x *= s; v.y *= s; v.z *= s; v.w *= s;
      *(float4*)&hps[jr][c4 * 4] = v;
    }
    __syncthreads();
    #pragma unroll
    for (int kk = 0; kk < 64; kk += 4) {
      float a0[4], a1[4], a2[4], a3[4];
      *(float4*)a0 = *(const float4*)&As[tr * 4 + 0][kk];
      *(float4*)a1 = *(const float4*)&As[tr * 4 + 1][kk];
      *(float4*)a2 = *(const float4*)&As[tr * 4 + 2][kk];
      *(float4*)a3 = *(const float4*)&As[tr * 4 + 3][kk];
      #pragma unroll
      for (int q = 0; q < 4; q++) {
        float4 w = *(const float4*)&hps[kk + q][tc * 4];
        acc[0].x += a0[q] * w.x; acc[0].y += a0[q] * w.y; acc[0].z += a0[q] * w.z; acc[0].w += a0[q] * w.w;
        acc[1].x += a1[q] * w.x; acc[1].y += a1[q] * w.y; acc[1].z += a1[q] * w.z; acc[1].w += a1[q] * w.w;
        acc[2].x += a2[q] * w.x; acc[2].y += a2[q] * w.y; acc[2].z += a2[q] * w.z; acc[2].w += a2[q] * w.w;
        acc[3].x += a3[q] * w.x; acc[3].y += a3[q] * w.y; acc[3].z += a3[q] * w.z; acc[3].w += a3[q] * w.w;
      }
    }
  }
  float* Hx = ks ? Hpb : Hpa;
  #pragma unroll
  for (int rr = 0; rr < 4; rr++) {
    int row = b * N_ + row0 + tr * 4 + rr;
    float s = dinv[row];
    float4 v = acc[rr];
    v.x *= s; v.y *= s; v.z *= s; v.w *= s;
    *(float4*)&Hx[(size_t)row * 128 + tc * 4] = v;
  }
}

// Z = espre + [Hp|h] @ WU -> gates -> c,h update -> hp=h@Wpe -> out[t]=out[t-1]+h@Wout+bout
// grid: 256 blocks of 16 rows
__global__ __launch_bounds__(256) void k_cell(
    const float* __restrict__ Hpa, const float* __restrict__ Hpb,
    float* __restrict__ hbuf, const float* __restrict__ espre,
    const float* __restrict__ WU, const float* __restrict__ Wpe,
    const float* __restrict__ Wout, const float* __restrict__ bout,
    float* __restrict__ cst, float* __restrict__ hp,
    float* __restrict__ out, int tstep) {
  __shared__ float xh[16][256];
  __shared__ float wus[64][128];
  __shared__ float hnew[16][128];
  const int t = threadIdx.x;
  const int row0 = blockIdx.x * 16;   // global row
  // phase 1: xh = [Hpa+Hpb | h]
  {
    const float4* Ha = (const float4*)Hpa;
    const float4* Hb = (const float4*)Hpb;
    const float4* Hh = (const float4*)hbuf;
    #pragma unroll
    for (int i = 0; i < 2; i++) {
      int idx = t + i * 256;
      int r = idx >> 5, c4 = idx & 31;
      float4 va = Ha[(size_t)(row0 + r) * 32 + c4];
      float4 vb = Hb[(size_t)(row0 + r) * 32 + c4];
      float4 v = make_float4(va.x + vb.x, va.y + vb.y, va.z + vb.z, va.w + vb.w);
      *(float4*)&xh[r][c4 * 4] = v;
      float4 vh = Hh[(size_t)(row0 + r) * 32 + c4];
      *(float4*)&xh[r][128 + c4 * 4] = vh;
    }
  }
  const int ct = t & 31, rg = t >> 5;   // cols ct*4, rows rg*2+{0,1}
  float4 zacc[4][2];
  #pragma unroll
  for (int p = 0; p < 4; p++) {
    zacc[p][0] = *(const float4*)&espre[(size_t)(row0 + rg * 2 + 0) * 512 + p * 128 + ct * 4];
    zacc[p][1] = *(const float4*)&espre[(size_t)(row0 + rg * 2 + 1) * 512 + p * 128 + ct * 4];
  }
  // phase 2: Z accumulation, WU staged in LDS
  #pragma unroll
  for (int p = 0; p < 4; p++) {
    float4 acc0 = zacc[p][0], acc1 = zacc[p][1];
    for (int kt = 0; kt < 4; kt++) {
      __syncthreads();
      #pragma unroll
      for (int i = 0; i < 8; i++) {
        int idx = t + i * 256;
        int kk = idx >> 5, c4 = idx & 31;
        *(float4*)&wus[kk][c4 * 4] =
            *(const float4*)&WU[(size_t)(kt * 64 + kk) * 512 + p * 128 + c4 * 4];
      }
      __syncthreads();
      #pragma unroll
      for (int kk = 0; kk < 64; kk += 4) {
        float xa[4], xb[4];
        *(float4*)xa = *(const float4*)&xh[rg * 2 + 0][kt * 64 + kk];
        *(float4*)xb = *(const float4*)&xh[rg * 2 + 1][kt * 64 + kk];
        #pragma unroll
        for (int q = 0; q < 4; q++) {
          float4 w = *(const float4*)&wus[kk + q][ct * 4];
          acc0.x += xa[q] * w.x; acc0.y += xa[q] * w.y; acc0.z += xa[q] * w.z; acc0.w += xa[q] * w.w;
          acc1.x += xb[q] * w.x; acc1.y += xb[q] * w.y; acc1.z += xb[q] * w.z; acc1.w += xb[q] * w.w;
        }
      }
    }
    zacc[p][0] = acc0; zacc[p][1] = acc1;
  }
  // phase 3: gates + state update (in registers)
  #pragma unroll
  for (int rr = 0; rr < 2; rr++) {
    int row = row0 + rg * 2 + rr;
    float zi[4], zf[4], zg[4], zo[4], co[4], cv[4], hv[4];
    *(float4*)zi = zacc[0][rr];
    *(float4*)zf = zacc[1][rr];
    *(float4*)zg = zacc[2][rr];
    *(float4*)zo = zacc[3][rr];
    *(float4*)co = *(const float4*)&cst[(size_t)row * 128 + ct * 4];
    #pragma unroll
    for (int q = 0; q < 4; q++) {
      float it = sigm(zi[q]), ft = sigm(zf[q]);
      float gt = tanh_fast(zg[q]), ot = sigm(zo[q]);
      cv[q] = ft * co[q] + it * gt;
      hv[q] = ot * tanh_fast(cv[q]);
    }
    *(float4*)&cst[(size_t)row * 128 + ct * 4] = *(float4*)cv;
    *(float4*)&hnew[rg * 2 + rr][ct * 4] = *(float4*)hv;
    *(float4*)&hbuf[(size_t)row * 128 + ct * 4] = *(float4*)hv;
  }
  __syncthreads();
  // phase 4: hp = hnew @ Wpe (staged)
  float4 pacc0 = make_float4(0.f, 0.f, 0.f, 0.f);
  float4 pacc1 = make_float4(0.f, 0.f, 0.f, 0.f);
  for (int kt = 0; kt < 2; kt++) {
    __syncthreads();
    #pragma unroll
    for (int i = 0; i < 8; i++) {
      int idx = t + i * 256;
      int kk = idx >> 5, c4 = idx & 31;
      *(float4*)&wus[kk][c4 * 4] =
          *(const float4*)&Wpe[(size_t)(kt * 64 + kk) * 128 + c4 * 4];
    }
    __syncthreads();
    #pragma unroll
    for (int kk = 0; kk < 64; kk += 4) {
      float xa[4], xb[4];
      *(float4*)xa = *(const float4*)&hnew[rg * 2 + 0][kt * 64 + kk];
      *(float4*)xb = *(const float4*)&hnew[rg * 2 + 1][kt * 64 + kk];
      #pragma unroll
      for (int q = 0; q < 4; q++) {
        float4 w = *(const float4*)&wus[kk + q][ct * 4];
        pacc0.x += xa[q] * w.x; pacc0.y += xa[q] * w.y; pacc0.z += xa[q] * w.z; pacc0.w += xa[q] * w.w;
        pacc1.x += xb[q] * w.x; pacc1.y += xb[q] * w.y; pacc1.z += xb[q] * w.z; pacc1.w += xb[q] * w.w;
      }
    }
  }
  *(float4*)&hp[(size_t)(row0 + rg * 2 + 0) * 128 + ct * 4] = pacc0;
  *(float4*)&hp[(size_t)(row0 + rg * 2 + 1) * 128 + ct * 4] = pacc1;
  // phase 5: out[t] = out[t-1] + hnew @ Wout + bout (Wout fully staged: 32KB)
  __syncthreads();
  float* wflat = &wus[0][0];
  #pragma unroll
  for (int i = 0; i < 8; i++) {
    ((float4*)wflat)[t + i * 256] = ((const float4*)Wout)[t + i * 256];
  }
  __syncthreads();
  const int c16 = t & 15, r16 = t >> 4;   // col c16*4, row r16
  float oa[4] = {0.f, 0.f, 0.f, 0.f};
  #pragma unroll
  for (int kk = 0; kk < 128; kk += 4) {
    float xa[4];
    *(float4*)xa = *(const float4*)&hnew[r16][kk];
    #pragma unroll
    for (int q = 0; q < 4; q++) {
      float4 w = *(const float4*)&wflat[(size_t)(kk + q) * 64 + c16 * 4];
      oa[0] += xa[q] * w.x; oa[1] += xa[q] * w.y; oa[2] += xa[q] * w.z; oa[3] += xa[q] * w.w;
    }
  }
  float bo[4];
  *(float4*)bo = *(const float4*)&bout[c16 * 4];
  size_t ob = ((size_t)(row0 + r16) * T_ + tstep) * NIN_ + c16 * 4;
  float pv[4];
  *(float4*)pv = *(const float4*)&out[ob - NIN_];
  float res[4];
  res[0] = pv[0] + oa[0] + bo[0];
  res[1] = pv[1] + oa[1] + bo[1];
  res[2] = pv[2] + oa[2] + bo[2];
  res[3] = pv[3] + oa[3] + bo[3];
  *(float4*)&out[ob] = *(float4*)res;
}

extern "C" void kernel_launch(void* const* d_in, const int* in_sizes, int n_in,
                              void* d_out, int out_size, void* d_ws, size_t ws_size,
                              hipStream_t stream) {
  const float* X    = (const float*)d_in[0];
  const float* A    = (const float*)d_in[1];
  const float* Wse  = (const float*)d_in[2];
  const float* bse  = (const float*)d_in[3];
  const float* Wpe  = (const float*)d_in[4];
  const float* bpe  = (const float*)d_in[5];
  const float* Wii  = (const float*)d_in[6];
  const float* bii  = (const float*)d_in[7];
  const float* Whi  = (const float*)d_in[8];
  const float* bhi  = (const float*)d_in[9];
  const float* Wif  = (const float*)d_in[10];
  const float* bif_ = (const float*)d_in[11];
  const float* Whf  = (const float*)d_in[12];
  const float* bhf  = (const float*)d_in[13];
  const float* Wig  = (const float*)d_in[14];
  const float* big_ = (const float*)d_in[15];
  const float* Whg  = (const float*)d_in[16];
  const float* bhg  = (const float*)d_in[17];
  const float* Wio  = (const float*)d_in[18];
  const float* bio  = (const float*)d_in[19];
  const float* Who  = (const float*)d_in[20];
  const float* bho  = (const float*)d_in[21];
  const float* Wout = (const float*)d_in[22];
  const float* bout = (const float*)d_in[23];
  float* out = (float*)d_out;
  float* ws  = (float*)d_ws;

  float* dinv  = ws;                     // 4096
  float* hp    = dinv + 4096;            // 4096*128
  float* Hpa   = hp + (size_t)NR_ * 128;
  float* Hpb   = Hpa + (size_t)NR_ * 128;
  float* hbuf  = Hpb + (size_t)NR_ * 128;
  float* cst   = hbuf + (size_t)NR_ * 128;
  float* espre = cst + (size_t)NR_ * 128;   // 4096*512
  float* WU    = espre + (size_t)NR_ * 512; // 256*512
  float* bcat  = WU + 256 * 512;            // 512

  hipMemsetAsync(hp,   0, (size_t)NR_ * 128 * sizeof(float), stream);
  hipMemsetAsync(hbuf, 0, (size_t)NR_ * 128 * sizeof(float), stream);
  hipMemsetAsync(cst,  0, (size_t)NR_ * 128 * sizeof(float), stream);

  k_dinv<<<NR_ / 4, 256, 0, stream>>>(A, dinv);
  k_wu<<<512, 256, 0, stream>>>(Wii, Wif, Wig, Wio, Whi, Whf, Whg, Who, WU);
  k_bcat<<<2, 256, 0, stream>>>(bii, bif_, big_, bio, bhi, bhf, bhg, bho, bpe,
                                Wii, Wif, Wig, Wio, bcat);
  k_espre<<<256, 256, 0, stream>>>(X, Wse, bse, Wii, Wif, Wig, Wio, bcat,
                                   espre, out);
  for (int tt = 1; tt < T_; tt++) {
    k_graph<<<256, 256, 0, stream>>>(A, dinv, hp, Hpa, Hpb);
    k_cell<<<256, 256, 0, stream>>>(Hpa, Hpb, hbuf, espre, WU, Wpe, Wout, bout,
                                    cst, hp, out, tt);
  }
}

// Round 2
// 1218.084 us; speedup vs baseline: 4.8238x; 4.8238x over previous
//
#include <hip/hip_runtime.h>
#include <math.h>

#define B_ 8
#define N_ 512
#define T_ 64
#define NIN_ 64
#define NE_ 128
#define NH_ 128
#define NR_ 4096   // B*N

typedef __attribute__((ext_vector_type(8))) short s8_t;   // 8 bf16 = 16B
typedef __attribute__((ext_vector_type(4))) short s4_t;   // 4 bf16 = 8B
typedef __attribute__((ext_vector_type(4))) float f4_t;

__device__ __forceinline__ float sigm(float x) {
  x = fminf(fmaxf(x, -30.f), 30.f);
  return 1.f / (1.f + __expf(-x));
}
__device__ __forceinline__ float tanh_fast(float x) {
  x = fminf(fmaxf(x, -15.f), 15.f);
  float e = __expf(2.f * x);
  return (e - 1.f) / (e + 1.f);
}
__device__ __forceinline__ unsigned short f2b(float f) {
  union { float f; unsigned u; } v; v.f = f;
  unsigned r = (v.u + 0x7FFFu + ((v.u >> 16) & 1u)) >> 16;
  return (unsigned short)r;
}

// ---------------- setup kernels (one-time) ----------------

// dinv[row] = rowsum(A) > 0 ? rsqrt(rowsum) : 0
__global__ __launch_bounds__(256) void k_dinv(const float* __restrict__ A,
                                              float* __restrict__ dinv) {
  int row = blockIdx.x * 4 + (threadIdx.x >> 6);
  int lane = threadIdx.x & 63;
  const float* a = A + (size_t)row * N_;
  float s = 0.f;
  for (int j = lane; j < N_; j += 64) s += a[j];
  #pragma unroll
  for (int off = 32; off > 0; off >>= 1) s += __shfl_down(s, off);
  if (lane == 0) dinv[row] = (s > 0.f) ? rsqrtf(s) : 0.f;
}

// Ans (bf16, row-major [4096][512]) = dinv_i * A * dinv_j
__global__ __launch_bounds__(256) void k_ans(const float* __restrict__ A,
                                             const float* __restrict__ dinv,
                                             unsigned short* __restrict__ Ans) {
  int idx = blockIdx.x * 256 + threadIdx.x;   // 4 elems each, 2048 blocks
  int base = idx * 4;
  int row = base >> 9, c0 = base & 511;
  int b = row >> 9;                            // batch
  float di = dinv[row];
  float4 a = *(const float4*)&A[(size_t)row * 512 + c0];
  s4_t o;
  o[0] = (short)f2b(a.x * di * dinv[b * 512 + c0 + 0]);
  o[1] = (short)f2b(a.y * di * dinv[b * 512 + c0 + 1]);
  o[2] = (short)f2b(a.z * di * dinv[b * 512 + c0 + 2]);
  o[3] = (short)f2b(a.w * di * dinv[b * 512 + c0 + 3]);
  *(s4_t*)&Ans[base] = o;
}

// WC (fp32, [128][512]) = Wpe @ concat(Wx*[128:256,:])
__global__ __launch_bounds__(256) void k_wc(
    const float* __restrict__ Wpe,
    const float* __restrict__ Wii, const float* __restrict__ Wif,
    const float* __restrict__ Wig, const float* __restrict__ Wio,
    float* __restrict__ WC) {
  int idx = blockIdx.x * 256 + threadIdx.x;    // 65536
  int k = idx >> 9, col = idx & 511, g = col >> 7, j = col & 127;
  const float* Wx = (g == 0) ? Wii : (g == 1) ? Wif : (g == 2) ? Wig : Wio;
  float s = 0.f;
  for (int m = 0; m < 128; m++)
    s += Wpe[(size_t)k * 128 + m] * Wx[(size_t)(128 + m) * 128 + j];
  WC[idx] = s;
}

// WUP2 (bf16 k-packed [(256/8)][512][8]): rows 0:128 = WC, 128:256 = Wh*
__global__ __launch_bounds__(256) void k_pack_wu2(
    const float* __restrict__ WC,
    const float* __restrict__ Whi, const float* __restrict__ Whf,
    const float* __restrict__ Whg, const float* __restrict__ Who,
    unsigned short* __restrict__ WUP2) {
  int idx = blockIdx.x * 256 + threadIdx.x;    // 131072
  int k = idx >> 9, col = idx & 511, g = col >> 7, j = col & 127;
  float v;
  if (k < 128) v = WC[(size_t)k * 512 + col];
  else {
    const float* Wh = (g == 0) ? Whi : (g == 1) ? Whf : (g == 2) ? Whg : Who;
    v = Wh[(size_t)(k - 128) * 128 + j];
  }
  WUP2[((size_t)(k >> 3) * 512 + col) * 8 + (k & 7)] = f2b(v);
}

// WoutP (bf16 k-packed [(128/8)][64][8])
__global__ __launch_bounds__(256) void k_pack_wout(
    const float* __restrict__ Wout, unsigned short* __restrict__ WoutP) {
  int idx = blockIdx.x * 256 + threadIdx.x;    // 8192
  int k = idx >> 6, c = idx & 63;
  WoutP[((size_t)(k >> 3) * 64 + c) * 8 + (k & 7)] = f2b(Wout[(size_t)k * 64 + c]);
}

// bcat[col] = bx + bh + bpe @ W*[128:256]
__global__ __launch_bounds__(256) void k_bcat(
    const float* __restrict__ bii, const float* __restrict__ bif,
    const float* __restrict__ big, const float* __restrict__ bio,
    const float* __restrict__ bhi, const float* __restrict__ bhf,
    const float* __restrict__ bhg, const float* __restrict__ bho,
    const float* __restrict__ bpe,
    const float* __restrict__ Wii, const float* __restrict__ Wif,
    const float* __restrict__ Wig, const float* __restrict__ Wio,
    float* __restrict__ bcat) {
  int col = blockIdx.x * 256 + threadIdx.x;   // < 512
  int g = col >> 7, j = col & 127;
  const float* bx = (g == 0) ? bii : (g == 1) ? bif : (g == 2) ? big : bio;
  const float* bh = (g == 0) ? bhi : (g == 1) ? bhf : (g == 2) ? bhg : bho;
  const float* Wx = (g == 0) ? Wii : (g == 1) ? Wif : (g == 2) ? Wig : Wio;
  float s = bx[j] + bh[j];
  for (int k = 0; k < NE_; k++) s += bpe[k] * Wx[(size_t)(128 + k) * NH_ + j];
  bcat[col] = s;
}

// es = X0@Wse + bse ; espre = es@W*[0:128] + bcat ; out[:, t=0] = X0
__global__ __launch_bounds__(256) void k_espre(
    const float* __restrict__ X, const float* __restrict__ Wse,
    const float* __restrict__ bse,
    const float* __restrict__ Wii, const float* __restrict__ Wif,
    const float* __restrict__ Wig, const float* __restrict__ Wio,
    const float* __restrict__ bcat,
    float* __restrict__ espre, float* __restrict__ out) {
  __shared__ float x0[16][64];
  __shared__ float es[16][128];
  const int t = threadIdx.x;
  const int row0 = blockIdx.x * 16;
  for (int i = t; i < 1024; i += 256) {
    int r = i >> 6, c = i & 63;
    float v = X[((size_t)(row0 + r) * T_) * NIN_ + c];
    x0[r][c] = v;
    out[((size_t)(row0 + r) * T_) * NIN_ + c] = v;
  }
  __syncthreads();
  for (int i = t; i < 2048; i += 256) {
    int r = i >> 7, j = i & 127;
    float s = bse[j];
    for (int k = 0; k < NIN_; k++) s += x0[r][k] * Wse[(size_t)k * NE_ + j];
    es[r][j] = s;
  }
  __syncthreads();
  for (int i = t; i < 8192; i += 256) {
    int r = i >> 9, col = i & 511, g = col >> 7, j = col & 127;
    const float* Wx = (g == 0) ? Wii : (g == 1) ? Wif : (g == 2) ? Wig : Wio;
    float s = bcat[col];
    for (int k = 0; k < NE_; k++) s += es[r][k] * Wx[(size_t)k * NH_ + j];
    espre[(size_t)(row0 + r) * 512 + col] = s;
  }
}

// ---------------- per-step kernels (MFMA bf16) ----------------

// G = Ans @ h    (per batch: [512x512] @ [512x128])
// grid 256: block = 16 rows; 4 waves, wave w covers cols 32w..32w+31
__global__ __launch_bounds__(256) void k_graph(
    const unsigned short* __restrict__ Ans,
    const unsigned short* __restrict__ hP,   // k-packed [(512/8)][128][8] per batch
    unsigned short* __restrict__ G) {
  __shared__ __align__(16) unsigned short as[16][520];
  const int t = threadIdx.x;
  const int gr0 = blockIdx.x * 16;
  const int b = blockIdx.x >> 5;
  #pragma unroll
  for (int i = 0; i < 4; i++) {                // stage A rows 16x512 bf16
    int idx = t + i * 256;
    int r = idx >> 6, c8 = idx & 63;
    *(s8_t*)&as[r][c8 * 8] = *(const s8_t*)&Ans[(size_t)(gr0 + r) * 512 + c8 * 8];
  }
  __syncthreads();
  const int l = t & 63, w = t >> 6, m = l & 15, kg = l >> 4;
  const unsigned short* hPb = hP + (size_t)b * 65536;
  f4_t acc[2] = {{0.f,0.f,0.f,0.f},{0.f,0.f,0.f,0.f}};
  for (int kc = 0; kc < 16; kc++) {
    int k0 = kc * 32;
    s8_t a = *(const s8_t*)&as[m][k0 + kg * 8];
    #pragma unroll
    for (int nt = 0; nt < 2; nt++) {
      int n = w * 32 + nt * 16 + m;
      s8_t bfr = *(const s8_t*)&hPb[((size_t)((k0 >> 3) + kg) * 128 + n) * 8];
      acc[nt] = __builtin_amdgcn_mfma_f32_16x16x32_bf16(a, bfr, acc[nt], 0, 0, 0);
    }
  }
  #pragma unroll
  for (int nt = 0; nt < 2; nt++)
    #pragma unroll
    for (int r = 0; r < 4; r++) {
      int row = gr0 + kg * 4 + r, col = w * 32 + nt * 16 + m;
      G[(size_t)row * 128 + col] = f2b(acc[nt][r]);
    }
}

// Z = espre + [G|h] @ WUP2 -> gates -> c,h -> out[t] = out[t-1] + h@Wout + bout
// grid 256: block = 16 rows; wave w computes gate w (128 cols)
__global__ __launch_bounds__(256) void k_cell(
    const unsigned short* __restrict__ G,
    unsigned short* __restrict__ hb,          // bf16 row-major [4096][128]
    const float* __restrict__ espre,
    const unsigned short* __restrict__ WUP2,
    const unsigned short* __restrict__ WoutP,
    const float* __restrict__ bout,
    float* __restrict__ cst,
    unsigned short* __restrict__ hP,
    float* __restrict__ out, int tstep) {
  __shared__ __align__(16) unsigned short xh[16][264];
  __shared__ __align__(16) float zb[4][16][132];
  __shared__ __align__(16) unsigned short hn[16][136];
  const int t = threadIdx.x;
  const int r0 = blockIdx.x * 16;
  // phase A: xh = [G | h] bf16
  #pragma unroll
  for (int i = 0; i < 2; i++) {
    int idx = t + i * 256;
    int r = idx >> 5, c8 = idx & 31;
    const unsigned short* src = (c8 < 16)
        ? &G[(size_t)(r0 + r) * 128 + c8 * 8]
        : &hb[(size_t)(r0 + r) * 128 + (c8 - 16) * 8];
    *(s8_t*)&xh[r][c8 * 8] = *(const s8_t*)src;
  }
  __syncthreads();
  const int l = t & 63, w = t >> 6, m = l & 15, kg = l >> 4;
  // phase B: Z accumulation (acc init from espre)
  f4_t acc[8];
  #pragma unroll
  for (int nt = 0; nt < 8; nt++)
    #pragma unroll
    for (int r = 0; r < 4; r++)
      acc[nt][r] = espre[(size_t)(r0 + kg * 4 + r) * 512 + w * 128 + nt * 16 + m];
  for (int kc = 0; kc < 8; kc++) {
    int k0 = kc * 32;
    s8_t a = *(const s8_t*)&xh[m][k0 + kg * 8];
    #pragma unroll
    for (int nt = 0; nt < 8; nt++) {
      s8_t bfr = *(const s8_t*)&WUP2[((size_t)((k0 >> 3) + kg) * 512 + w * 128 + nt * 16 + m) * 8];
      acc[nt] = __builtin_amdgcn_mfma_f32_16x16x32_bf16(a, bfr, acc[nt], 0, 0, 0);
    }
  }
  #pragma unroll
  for (int nt = 0; nt < 8; nt++)
    #pragma unroll
    for (int r = 0; r < 4; r++)
      zb[w][kg * 4 + r][nt * 16 + m] = acc[nt][r];
  __syncthreads();
  // phase C: cell update; thread owns (row = t>>4, cols (t&15)*8..+7)
  {
    int row = t >> 4, cg = t & 15;
    float zi[8], zf[8], zg[8], zo[8], co[8];
    *(f4_t*)&zi[0] = *(f4_t*)&zb[0][row][cg * 8];
    *(f4_t*)&zi[4] = *(f4_t*)&zb[0][row][cg * 8 + 4];
    *(f4_t*)&zf[0] = *(f4_t*)&zb[1][row][cg * 8];
    *(f4_t*)&zf[4] = *(f4_t*)&zb[1][row][cg * 8 + 4];
    *(f4_t*)&zg[0] = *(f4_t*)&zb[2][row][cg * 8];
    *(f4_t*)&zg[4] = *(f4_t*)&zb[2][row][cg * 8 + 4];
    *(f4_t*)&zo[0] = *(f4_t*)&zb[3][row][cg * 8];
    *(f4_t*)&zo[4] = *(f4_t*)&zb[3][row][cg * 8 + 4];
    int gr = r0 + row;
    *(f4_t*)&co[0] = *(const f4_t*)&cst[(size_t)gr * 128 + cg * 8];
    *(f4_t*)&co[4] = *(const f4_t*)&cst[(size_t)gr * 128 + cg * 8 + 4];
    float cv[8];
    s8_t hv8;
    unsigned short hbits[8];
    #pragma unroll
    for (int q = 0; q < 8; q++) {
      float it = sigm(zi[q]), ft = sigm(zf[q]);
      float gt = tanh_fast(zg[q]), ot = sigm(zo[q]);
      cv[q] = ft * co[q] + it * gt;
      float hvq = ot * tanh_fast(cv[q]);
      hbits[q] = f2b(hvq);
      hv8[q] = (short)hbits[q];
    }
    *(f4_t*)&cst[(size_t)gr * 128 + cg * 8] = *(f4_t*)&cv[0];
    *(f4_t*)&cst[(size_t)gr * 128 + cg * 8 + 4] = *(f4_t*)&cv[4];
    *(s8_t*)&hb[(size_t)gr * 128 + cg * 8] = hv8;
    *(s8_t*)&hn[row][cg * 8] = hv8;
    // k-packed h for next step's graph GEMM
    size_t pbase = (size_t)(gr >> 9) * 65536 + (size_t)((gr & 511) >> 3) * 1024 + (gr & 7);
    #pragma unroll
    for (int q = 0; q < 8; q++)
      hP[pbase + (size_t)(cg * 8 + q) * 8] = hbits[q];
  }
  __syncthreads();
  // phase E: out[t] = out[t-1] + hn @ WoutP + bout ; wave w covers cols 16w..+15
  f4_t o = {0.f, 0.f, 0.f, 0.f};
  for (int kc = 0; kc < 4; kc++) {
    int k0 = kc * 32;
    s8_t a = *(const s8_t*)&hn[m][k0 + kg * 8];
    s8_t bfr = *(const s8_t*)&WoutP[((size_t)((k0 >> 3) + kg) * 64 + w * 16 + m) * 8];
    o = __builtin_amdgcn_mfma_f32_16x16x32_bf16(a, bfr, o, 0, 0, 0);
  }
  int col = w * 16 + m;
  float bo = bout[col];
  #pragma unroll
  for (int r = 0; r < 4; r++) {
    int row = r0 + kg * 4 + r;
    size_t ob = ((size_t)row * T_ + tstep) * NIN_ + col;
    out[ob] = out[ob - NIN_] + o[r] + bo;
  }
}

extern "C" void kernel_launch(void* const* d_in, const int* in_sizes, int n_in,
                              void* d_out, int out_size, void* d_ws, size_t ws_size,
                              hipStream_t stream) {
  const float* X    = (const float*)d_in[0];
  const float* A    = (const float*)d_in[1];
  const float* Wse  = (const float*)d_in[2];
  const float* bse  = (const float*)d_in[3];
  const float* Wpe  = (const float*)d_in[4];
  const float* bpe  = (const float*)d_in[5];
  const float* Wii  = (const float*)d_in[6];
  const float* bii  = (const float*)d_in[7];
  const float* Whi  = (const float*)d_in[8];
  const float* bhi  = (const float*)d_in[9];
  const float* Wif  = (const float*)d_in[10];
  const float* bif_ = (const float*)d_in[11];
  const float* Whf  = (const float*)d_in[12];
  const float* bhf  = (const float*)d_in[13];
  const float* Wig  = (const float*)d_in[14];
  const float* big_ = (const float*)d_in[15];
  const float* Whg  = (const float*)d_in[16];
  const float* bhg  = (const float*)d_in[17];
  const float* Wio  = (const float*)d_in[18];
  const float* bio  = (const float*)d_in[19];
  const float* Who  = (const float*)d_in[20];
  const float* bho  = (const float*)d_in[21];
  const float* Wout = (const float*)d_in[22];
  const float* bout = (const float*)d_in[23];
  float* out = (float*)d_out;
  char* ws = (char*)d_ws;

  size_t off = 0;
  float* dinv = (float*)(ws + off);          off += 4096 * 4;
  unsigned short* Ans = (unsigned short*)(ws + off);  off += (size_t)NR_ * 512 * 2;
  unsigned short* G   = (unsigned short*)(ws + off);  off += (size_t)NR_ * 128 * 2;
  unsigned short* hb  = (unsigned short*)(ws + off);  off += (size_t)NR_ * 128 * 2;
  unsigned short* hP  = (unsigned short*)(ws + off);  off += (size_t)NR_ * 128 * 2;
  float* cst   = (float*)(ws + off);         off += (size_t)NR_ * 128 * 4;
  float* espre = (float*)(ws + off);         off += (size_t)NR_ * 512 * 4;
  float* WC    = (float*)(ws + off);         off += (size_t)128 * 512 * 4;
  unsigned short* WUP2  = (unsigned short*)(ws + off); off += (size_t)256 * 512 * 2;
  unsigned short* WoutP = (unsigned short*)(ws + off); off += (size_t)128 * 64 * 2;
  float* bcat = (float*)(ws + off);          off += 512 * 4;

  hipMemsetAsync(hb,  0, (size_t)NR_ * 128 * 2, stream);
  hipMemsetAsync(hP,  0, (size_t)NR_ * 128 * 2, stream);
  hipMemsetAsync(cst, 0, (size_t)NR_ * 128 * 4, stream);

  k_dinv<<<NR_ / 4, 256, 0, stream>>>(A, dinv);
  k_ans<<<2048, 256, 0, stream>>>(A, dinv, Ans);
  k_wc<<<256, 256, 0, stream>>>(Wpe, Wii, Wif, Wig, Wio, WC);
  k_pack_wu2<<<512, 256, 0, stream>>>(WC, Whi, Whf, Whg, Who, WUP2);
  k_pack_wout<<<32, 256, 0, stream>>>(Wout, WoutP);
  k_bcat<<<2, 256, 0, stream>>>(bii, bif_, big_, bio, bhi, bhf, bhg, bho, bpe,
                                Wii, Wif, Wig, Wio, bcat);
  k_espre<<<256, 256, 0, stream>>>(X, Wse, bse, Wii, Wif, Wig, Wio, bcat,
                                   espre, out);
  for (int tt = 1; tt < T_; tt++) {
    k_graph<<<256, 256, 0, stream>>>(Ans, hP, G);
    k_cell<<<256, 256, 0, stream>>>(G, hb, espre, WUP2, WoutP, bout,
                                    cst, hP, out, tt);
  }
}